// Round 9
// baseline (225.572 us; speedup 1.0000x reference)
//
#include <hip/hip_runtime.h>
#include <hip/hip_bf16.h>

#define ALPHA 0.2f
#define LOG2E 1.44269504f

// ws layout (bytes)
#define VB_OFFB 0                        // Vb: bf16 swizzled V, 6291456 B
#define XB_OFFB 6291456                  // Xb: bf16 X, 6291456 B
#define WB_OFFB (XB_OFFB + 6291456)      // Wb: bf16 swizzled W, 1179648 B
#define F1_OFFB (WB_OFFB + 1179648)
#define F2_OFFB (F1_OFFB + 131072)
#define WA_OFFB (F2_OFFB + 131072)       // waT fp32 16x768 (49152 B)

// INSTRUMENTATION ROUND: idempotent repeat loops make the real kernels
// longer than the ~40us harness fills so they surface in top-5 WITH
// counters. REP_* will be reverted to 1 next round.
#define REP_ATTN 4
#define REP_GEMM 4
#define REP_CVT 16
#define REP_F12 16

typedef __attribute__((ext_vector_type(8))) unsigned short us8;
typedef __attribute__((ext_vector_type(8))) short s8;
typedef __attribute__((ext_vector_type(4))) float f32x4;

__device__ inline unsigned short f2bf(float x) {
    __hip_bfloat16 h = __float2bfloat16(x);
    return reinterpret_cast<unsigned short&>(h);
}

__device__ __forceinline__ void gload16(const void* g, void* lds) {
    __builtin_amdgcn_global_load_lds((const unsigned int*)g, (unsigned int*)lds,
                                     16, 0, 0);
}

// ---------------------------------------------------------------------------
// cvt_x: X fp32 -> Xb bf16 (row-major [4096][768])
// ---------------------------------------------------------------------------
__global__ __launch_bounds__(256) void cvt_x(const float* __restrict__ X,
                                             unsigned short* __restrict__ Xb) {
    const int i = (blockIdx.x * 256 + threadIdx.x) * 8;
    for (int rep = 0; rep < REP_CVT; ++rep) {
        asm volatile("" ::: "memory");
        float4 v0 = *(const float4*)&X[i];
        float4 v1 = *(const float4*)&X[i + 4];
        ushort4 p0, p1;
        p0.x = f2bf(v0.x); p0.y = f2bf(v0.y); p0.z = f2bf(v0.z); p0.w = f2bf(v0.w);
        p1.x = f2bf(v1.x); p1.y = f2bf(v1.y); p1.z = f2bf(v1.z); p1.w = f2bf(v1.w);
        *(ushort4*)&Xb[i] = p0;
        *(ushort4*)&Xb[i + 4] = p1;
    }
}

// ---------------------------------------------------------------------------
// prep_w: blocks 0-287: W fp32 -> Wb bf16 B-frag order
//         blocks 288-303: waT[hw][k] = sum_f W[k][h*96+f]*a[which*96+f]
// ---------------------------------------------------------------------------
__global__ __launch_bounds__(256) void prep_w(const float* __restrict__ W,
                                              const float* __restrict__ a,
                                              unsigned short* __restrict__ Wb,
                                              float* __restrict__ waT) {
    if (blockIdx.x < 288) {
        const int id = blockIdx.x * 256 + threadIdx.x;   // 0..73727
        const int l = id & 63;
        const int ks = (id >> 6) & 1;
        const int cg4 = (id >> 7) & 3;
        const int kc = id >> 9;                          // kt*12 + ct
        const int kt = kc / 12;
        const int ct = kc - kt * 12;
        const int k0 = kt * 64 + ks * 32 + (l >> 4) * 8;
        const int n = ct * 64 + cg4 * 16 + (l & 15);
        ushort4 p0, p1;
        p0.x = f2bf(W[(size_t)(k0 + 0) * 768 + n]);
        p0.y = f2bf(W[(size_t)(k0 + 1) * 768 + n]);
        p0.z = f2bf(W[(size_t)(k0 + 2) * 768 + n]);
        p0.w = f2bf(W[(size_t)(k0 + 3) * 768 + n]);
        p1.x = f2bf(W[(size_t)(k0 + 4) * 768 + n]);
        p1.y = f2bf(W[(size_t)(k0 + 5) * 768 + n]);
        p1.z = f2bf(W[(size_t)(k0 + 6) * 768 + n]);
        p1.w = f2bf(W[(size_t)(k0 + 7) * 768 + n]);
        *(ushort4*)&Wb[(size_t)id * 8 + 0] = p0;
        *(ushort4*)&Wb[(size_t)id * 8 + 4] = p1;
    } else {
        __shared__ float a_s[96];
        const int hw = blockIdx.x - 288;
        const int h = hw & 7;
        const int which = hw >> 3;
        if (threadIdx.x < 96) a_s[threadIdx.x] = a[which * 96 + threadIdx.x];
        __syncthreads();
        for (int kk = 0; kk < 3; ++kk) {
            int k = threadIdx.x + kk * 256;
            const float* wr = &W[(size_t)k * 768 + h * 96];
            float s = 0.f;
#pragma unroll
            for (int q = 0; q < 24; ++q) {
                float4 wv = *(const float4*)&wr[q * 4];
                s += wv.x * a_s[q * 4] + wv.y * a_s[q * 4 + 1] +
                     wv.z * a_s[q * 4 + 2] + wv.w * a_s[q * 4 + 3];
            }
            waT[hw * 768 + k] = s;
        }
    }
}

// ---------------------------------------------------------------------------
// f12m_k: f[4096][16] = X @ waT^T via one 16-wide MFMA N-tile.
// ---------------------------------------------------------------------------
__global__ __launch_bounds__(64) void f12m_k(const float* __restrict__ X,
                                             const float* __restrict__ waT,
                                             float* __restrict__ f1,
                                             float* __restrict__ f2) {
    const int l = threadIdx.x;
    const int r0 = blockIdx.x * 16;        // global row base (b*1024+n)
    const int rr = l & 15;
    const int kq = l >> 4;                 // 0..3
    const float* xrow = X + (size_t)(r0 + rr) * 768 + kq * 8;
    const float* wrow = waT + (size_t)rr * 768 + kq * 8;   // rr = hw (B col)

    for (int rep = 0; rep < REP_F12; ++rep) {
        asm volatile("" ::: "memory");
        f32x4 acc = (f32x4){0.f, 0.f, 0.f, 0.f};
#pragma unroll
        for (int ks = 0; ks < 24; ++ks) {
            float4 xa = *(const float4*)(xrow + ks * 32);
            float4 xb = *(const float4*)(xrow + ks * 32 + 4);
            float4 wa = *(const float4*)(wrow + ks * 32);
            float4 wb = *(const float4*)(wrow + ks * 32 + 4);
            s8 af, bf;
            af[0] = (short)f2bf(xa.x); af[1] = (short)f2bf(xa.y);
            af[2] = (short)f2bf(xa.z); af[3] = (short)f2bf(xa.w);
            af[4] = (short)f2bf(xb.x); af[5] = (short)f2bf(xb.y);
            af[6] = (short)f2bf(xb.z); af[7] = (short)f2bf(xb.w);
            bf[0] = (short)f2bf(wa.x); bf[1] = (short)f2bf(wa.y);
            bf[2] = (short)f2bf(wa.z); bf[3] = (short)f2bf(wa.w);
            bf[4] = (short)f2bf(wb.x); bf[5] = (short)f2bf(wb.y);
            bf[6] = (short)f2bf(wb.z); bf[7] = (short)f2bf(wb.w);
            acc = __builtin_amdgcn_mfma_f32_16x16x32_bf16(af, bf, acc, 0, 0, 0);
        }
        const int hw = rr;
        float* dst = (hw < 8) ? f1 : f2;
        const int h = hw & 7;
#pragma unroll
        for (int r = 0; r < 4; ++r) {
            const int row = r0 + kq * 4 + r;
            const int b = row >> 10, n = row & 1023;
            dst[(((b << 3) + h) << 10) | n] = acc[r];
        }
    }
}

// ---------------------------------------------------------------------------
// gemm_mfma: Vb = bf16-swizzle(Xb @ W). Round-4 verified structure, 1D grid
// 768 with XCD-chunked bijective swizzle.
// ---------------------------------------------------------------------------
__global__ __launch_bounds__(256) void gemm_mfma(const unsigned short* __restrict__ Xb,
                                                 const unsigned short* __restrict__ Wb,
                                                 unsigned short* __restrict__ Vb) {
    __shared__ __align__(16) unsigned short Xs[2][4096];
    __shared__ __align__(16) unsigned short Ws[2][4096];

    const int tid = threadIdx.x;
    const int l = tid & 63;
    const int w = tid >> 6;
    const int wr = w >> 1, wc = w & 1;
    const int id = blockIdx.x;
    const int nid = (id & 7) * 96 + (id >> 3);
    const int bx = nid % 12;             // N-tile (64 cols)
    const int row0 = (nid / 12) * 64;    // M-tile (64 rows)

    const int xrow_base = w * 16 + (l >> 3);
    const int xkb_log8 = ((l & 7) ^ (l >> 3)) * 8;

    for (int rep = 0; rep < REP_GEMM; ++rep) {
        asm volatile("" ::: "memory");
        __syncthreads();
        f32x4 acc[2][2];
#pragma unroll
        for (int i = 0; i < 2; ++i)
#pragma unroll
            for (int j = 0; j < 2; ++j) acc[i][j] = (f32x4){0.f, 0.f, 0.f, 0.f};

        {
#pragma unroll
            for (int q = 0; q < 2; ++q) {
                const int g16 = w * 2 + q;
                gload16(Xb + (size_t)(row0 + xrow_base + q * 8) * 768 + xkb_log8,
                        &Xs[0][g16 * 512]);
                gload16(Wb + (size_t)(0 * 12 + bx) * 4096 + g16 * 512 + l * 8,
                        &Ws[0][g16 * 512]);
            }
        }

        int buf = 0;
        for (int kt = 0; kt < 12; ++kt) {
            __syncthreads();
            if (kt < 11) {
                const int k0n = (kt + 1) * 64;
#pragma unroll
                for (int q = 0; q < 2; ++q) {
                    const int g16 = w * 2 + q;
                    gload16(Xb + (size_t)(row0 + xrow_base + q * 8) * 768 + k0n + xkb_log8,
                            &Xs[buf ^ 1][g16 * 512]);
                    gload16(Wb + (size_t)((kt + 1) * 12 + bx) * 4096 + g16 * 512 + l * 8,
                            &Ws[buf ^ 1][g16 * 512]);
                }
            }
#pragma unroll
            for (int ks = 0; ks < 2; ++ks) {
                s8 af[2], bfr[2];
#pragma unroll
                for (int fr = 0; fr < 2; ++fr) {
                    const int row = wr * 32 + fr * 16 + (l & 15);
                    const int slot = (ks * 4 + (l >> 4)) ^ (row & 7);
                    af[fr] = *(const s8*)((const char*)&Xs[buf][0] + row * 128 + slot * 16);
                }
#pragma unroll
                for (int cg = 0; cg < 2; ++cg) {
                    bfr[cg] = *(const s8*)((const char*)&Ws[buf][0] +
                                           (((wc * 2 + cg) * 2 + ks) * 64 + l) * 16);
                }
#pragma unroll
                for (int fr = 0; fr < 2; ++fr)
#pragma unroll
                    for (int cg = 0; cg < 2; ++cg)
                        acc[fr][cg] = __builtin_amdgcn_mfma_f32_16x16x32_bf16(
                            af[fr], bfr[cg], acc[fr][cg], 0, 0, 0);
            }
            buf ^= 1;
        }

#pragma unroll
        for (int fr = 0; fr < 2; ++fr) {
#pragma unroll
            for (int cg = 0; cg < 2; ++cg) {
                const int jglob = row0 + wr * 32 + fr * 16 + (l >> 4) * 4;
                const int b = jglob >> 10;
                const int jn = jglob & 1023;
                const int jc = jn >> 7;
                const int ks4 = (jn >> 5) & 3;
                const int kg = (jn >> 3) & 3;
                const int e0 = jn & 7;
                const int g0 = bx * 64 + wc * 32 + cg * 16;
                const int h = g0 / 96;
                const int ft = (g0 - h * 96) >> 4;
                const int fc = l & 15;
                const size_t ibase =
                    (((((size_t)(b * 8 + h) * 8 + jc) * 4 + ks4) * 4 + kg) * 6 + ft) * 128 +
                    fc * 8 + e0;
                ushort4 pk;
                pk.x = f2bf(acc[fr][cg][0]);
                pk.y = f2bf(acc[fr][cg][1]);
                pk.z = f2bf(acc[fr][cg][2]);
                pk.w = f2bf(acc[fr][cg][3]);
                *(ushort4*)&Vb[ibase] = pk;
            }
        }
    }
}

// ---------------------------------------------------------------------------
// attn7_k: V-reuse attention (round-8 structure, unchanged except rep loop).
// ---------------------------------------------------------------------------
__global__ __launch_bounds__(256) void attn7_k(const unsigned short* __restrict__ Vb,
                                               const float* __restrict__ f1,
                                               const float* __restrict__ f2,
                                               const int* __restrict__ mask,
                                               float* __restrict__ out) {
    __shared__ __align__(16) unsigned short Vs[2][12288];
    __shared__ float g2_s[1024];

    const int tid = threadIdx.x;
    const int lane = tid & 63;
    const int w = tid >> 6;
    const int kg = lane >> 4;
    const int fcr = lane & 15;
    const int nid = (blockIdx.x & 7) * 64 + (blockIdx.x >> 3);
    const int it = nid & 15;       // 16 i-tiles of 64 rows
    const int bh = nid >> 4;
    const int b = bh >> 3;
    const int h = bh & 7;

    const size_t vbase = (size_t)bh * 98304;

    for (int rep = 0; rep < REP_ATTN; ++rep) {
        asm volatile("" ::: "memory");
        __syncthreads();
        for (int j = tid; j < 1024; j += 256) {
            float fv = f2[bh * 1024 + j] * LOG2E;
            g2_s[j] = (mask[b * 1024 + j] != 0) ? fv : -20000.f;
        }

        const float f1v = f1[bh * 1024 + it * 64 + w * 16 + fcr] * LOG2E;

#pragma unroll
        for (int r = 0; r < 6; ++r) {
            const int s = r * 256 + tid;           // 16B slot 0..1535
            gload16(Vb + vbase + (size_t)s * 8, &Vs[0][s * 8]);
        }

        f32x4 acc[6];
#pragma unroll
        for (int ft = 0; ft < 6; ++ft) acc[ft] = (f32x4){0.f, 0.f, 0.f, 0.f};
        float ls = 0.f;

        int buf = 0;
        for (int c = 0; c < 8; ++c) {
            __syncthreads();
            if (c < 7) {
#pragma unroll
                for (int r = 0; r < 6; ++r) {
                    const int s = r * 256 + tid;
                    gload16(Vb + vbase + (size_t)(c + 1) * 12288 + (size_t)s * 8,
                            &Vs[buf ^ 1][s * 8]);
                }
            }
            const unsigned short* vsb = &Vs[buf][0];
#pragma unroll
            for (int ks = 0; ks < 4; ++ks) {
                s8 af;
                const int jb = c * 128 + ks * 32 + kg * 8;
                float4 ga = *(const float4*)&g2_s[jb];
                float4 gb = *(const float4*)&g2_s[jb + 4];
                float g[8] = {ga.x, ga.y, ga.z, ga.w, gb.x, gb.y, gb.z, gb.w};
#pragma unroll
                for (int e = 0; e < 8; ++e) {
                    float t = f1v + g[e];
                    float lr = fmaxf(t, 0.f) + ALPHA * fminf(t, 0.f);
                    float pe = exp2f(lr);
                    ls += pe;
                    af[e] = (short)f2bf(pe);
                }
                const unsigned short* vp = vsb + ((ks * 4 + kg) * 6) * 128 + fcr * 8;
#pragma unroll
                for (int ft = 0; ft < 6; ++ft) {
                    us8 bvu = *(const us8*)(vp + ft * 128);
                    acc[ft] = __builtin_amdgcn_mfma_f32_16x16x32_bf16(
                        af, (s8)bvu, acc[ft], 0, 0, 0);
                }
            }
            buf ^= 1;
        }

        ls += __shfl_xor(ls, 16);
        ls += __shfl_xor(ls, 32);
        float inv[4];
#pragma unroll
        for (int r = 0; r < 4; ++r) inv[r] = 1.0f / __shfl(ls, kg * 4 + r);

        const int irow0 = it * 64 + w * 16 + kg * 4;
#pragma unroll
        for (int r = 0; r < 4; ++r) {
            const size_t ob = (size_t)(b * 1024 + irow0 + r) * 768 + h * 96 + fcr;
#pragma unroll
            for (int ft = 0; ft < 6; ++ft) {
                out[ob + ft * 16] = acc[ft][r] * inv[r];
            }
        }
    }
}

extern "C" void kernel_launch(void* const* d_in, const int* in_sizes, int n_in,
                              void* d_out, int out_size, void* d_ws, size_t ws_size,
                              hipStream_t stream) {
    const float* X = (const float*)d_in[0];
    const int* mask = (const int*)d_in[1];
    const float* W = (const float*)d_in[2];
    const float* a = (const float*)d_in[3];
    float* out = (float*)d_out;
    char* ws = (char*)d_ws;

    unsigned short* Vb = (unsigned short*)(ws + VB_OFFB);
    unsigned short* Xb = (unsigned short*)(ws + XB_OFFB);
    unsigned short* Wb = (unsigned short*)(ws + WB_OFFB);
    float* f1 = (float*)(ws + F1_OFFB);
    float* f2 = (float*)(ws + F2_OFFB);
    float* waT = (float*)(ws + WA_OFFB);

    cvt_x<<<1536, 256, 0, stream>>>(X, Xb);
    prep_w<<<304, 256, 0, stream>>>(W, a, Wb, waT);
    f12m_k<<<256, 64, 0, stream>>>(X, waT, f1, f2);
    gemm_mfma<<<768, 256, 0, stream>>>(Xb, Wb, Vb);
    attn7_k<<<512, 256, 0, stream>>>(Vb, f1, f2, mask, out);
}

// Round 10
// 72.849 us; speedup vs baseline: 3.0964x; 3.0964x over previous
//
#include <hip/hip_runtime.h>
#include <hip/hip_bf16.h>

#define ALPHA 0.2f
#define LOG2E 1.44269504f

// ws layout (bytes)
#define VB_OFFB 0                        // Vb: bf16 swizzled V, 6291456 B
#define WB_OFFB 6291456                  // Wb: bf16 swizzled W, 1179648 B
#define F1_OFFB (WB_OFFB + 1179648)      // f1: 32768 f32
#define F2_OFFB (F1_OFFB + 131072)       // f2: 32768 f32

typedef __attribute__((ext_vector_type(8))) unsigned short us8;
typedef __attribute__((ext_vector_type(8))) short s8;
typedef __attribute__((ext_vector_type(4))) float f32x4;

__device__ inline unsigned short f2bf(float x) {
    __hip_bfloat16 h = __float2bfloat16(x);
    return reinterpret_cast<unsigned short&>(h);
}

__device__ __forceinline__ void gload16(const void* g, void* lds) {
    __builtin_amdgcn_global_load_lds((const unsigned int*)g, (unsigned int*)lds,
                                     16, 0, 0);
}

// ---------------------------------------------------------------------------
// prep_w: blocks 0-287: W fp32 -> Wb bf16 B-frag order
//           Wb[kt(12)][ct(12)][cg4(4)][ks(2)][lane(64)][e(8)]
//         blocks 288-543: zero f1/f2 (65536 floats) for gemm_f atomics.
// ---------------------------------------------------------------------------
__global__ __launch_bounds__(256) void prep_w(const float* __restrict__ W,
                                              unsigned short* __restrict__ Wb,
                                              float* __restrict__ f12z) {
    if (blockIdx.x < 288) {
        const int id = blockIdx.x * 256 + threadIdx.x;   // 0..73727
        const int l = id & 63;
        const int ks = (id >> 6) & 1;
        const int cg4 = (id >> 7) & 3;
        const int kc = id >> 9;                          // kt*12 + ct
        const int kt = kc / 12;
        const int ct = kc - kt * 12;
        const int k0 = kt * 64 + ks * 32 + (l >> 4) * 8;
        const int n = ct * 64 + cg4 * 16 + (l & 15);
        ushort4 p0, p1;
        p0.x = f2bf(W[(size_t)(k0 + 0) * 768 + n]);
        p0.y = f2bf(W[(size_t)(k0 + 1) * 768 + n]);
        p0.z = f2bf(W[(size_t)(k0 + 2) * 768 + n]);
        p0.w = f2bf(W[(size_t)(k0 + 3) * 768 + n]);
        p1.x = f2bf(W[(size_t)(k0 + 4) * 768 + n]);
        p1.y = f2bf(W[(size_t)(k0 + 5) * 768 + n]);
        p1.z = f2bf(W[(size_t)(k0 + 6) * 768 + n]);
        p1.w = f2bf(W[(size_t)(k0 + 7) * 768 + n]);
        *(ushort4*)&Wb[(size_t)id * 8 + 0] = p0;
        *(ushort4*)&Wb[(size_t)id * 8 + 4] = p1;
    } else {
        const int idx = (blockIdx.x - 288) * 256 + threadIdx.x;  // 0..65535
        f12z[idx] = 0.f;
    }
}

// ---------------------------------------------------------------------------
// gemm_f: fused Wh GEMM + V-swizzle write + f1/f2 epilogue. NO LDS, NO
// barriers: A-frags read per-lane direct from fp32 X (L2-resident after XCD
// swizzle: 1.6 MB/XCD) with inline bf16 cvt; B-frags read coalesced from
// pre-swizzled Wb (1.2 MB, L2-resident). 768 blocks x 4 waves, each wave
// 32x32 output. Epilogue: Vb frag store (round-4 verified layout) and
// f1/f2 += (Wh . a1/a2) via 16-lane shfl reduce + one fp32 atomicAdd per
// row per 16-col group (12 adds/address total).
// ---------------------------------------------------------------------------
__global__ __launch_bounds__(256) void gemm_f(const float* __restrict__ X,
                                              const unsigned short* __restrict__ Wb,
                                              const float* __restrict__ a,
                                              unsigned short* __restrict__ Vb,
                                              float* __restrict__ f1,
                                              float* __restrict__ f2) {
    const int tid = threadIdx.x;
    const int l = tid & 63;
    const int w = tid >> 6;
    const int wr = w >> 1, wc = w & 1;
    // XCD-chunked bijective swizzle (768 = 8*96)
    const int nid = (blockIdx.x & 7) * 96 + (blockIdx.x >> 3);
    const int bx = nid % 12;             // N-tile (64 cols)
    const int row0 = (nid / 12) * 64;    // M-tile (64 rows)

    const int arow = row0 + wr * 32 + (l & 15);   // + fr*16
    const int kof = (l >> 4) * 8;

    f32x4 acc[2][2];
#pragma unroll
    for (int i = 0; i < 2; ++i)
#pragma unroll
        for (int j = 0; j < 2; ++j) acc[i][j] = (f32x4){0.f, 0.f, 0.f, 0.f};

    for (int kt = 0; kt < 12; ++kt) {
#pragma unroll
        for (int ks = 0; ks < 2; ++ks) {
            const int k = kt * 64 + ks * 32 + kof;
            s8 af[2], bfr[2];
#pragma unroll
            for (int fr = 0; fr < 2; ++fr) {
                const float* xp = X + (size_t)(arow + fr * 16) * 768 + k;
                float4 xa = *(const float4*)xp;
                float4 xb = *(const float4*)(xp + 4);
                af[fr][0] = (short)f2bf(xa.x); af[fr][1] = (short)f2bf(xa.y);
                af[fr][2] = (short)f2bf(xa.z); af[fr][3] = (short)f2bf(xa.w);
                af[fr][4] = (short)f2bf(xb.x); af[fr][5] = (short)f2bf(xb.y);
                af[fr][6] = (short)f2bf(xb.z); af[fr][7] = (short)f2bf(xb.w);
            }
#pragma unroll
            for (int cg = 0; cg < 2; ++cg) {
                const size_t wb_off =
                    ((((size_t)(kt * 12 + bx) * 4 + (wc * 2 + cg)) * 2 + ks) * 64 + l) * 8;
                bfr[cg] = (s8)(*(const us8*)&Wb[wb_off]);
            }
#pragma unroll
            for (int fr = 0; fr < 2; ++fr)
#pragma unroll
                for (int cg = 0; cg < 2; ++cg)
                    acc[fr][cg] = __builtin_amdgcn_mfma_f32_16x16x32_bf16(
                        af[fr], bfr[cg], acc[fr][cg], 0, 0, 0);
        }
    }

    // Epilogue 1: Vb swizzled bf16 store. C/D: col=l&15, row=(l>>4)*4+reg.
#pragma unroll
    for (int fr = 0; fr < 2; ++fr) {
#pragma unroll
        for (int cg = 0; cg < 2; ++cg) {
            const int jglob = row0 + wr * 32 + fr * 16 + (l >> 4) * 4;
            const int b = jglob >> 10;
            const int jn = jglob & 1023;
            const int jc = jn >> 7;
            const int ks4 = (jn >> 5) & 3;
            const int kg = (jn >> 3) & 3;
            const int e0 = jn & 7;
            const int g0 = bx * 64 + wc * 32 + cg * 16;
            const int h = g0 / 96;
            const int ft = (g0 - h * 96) >> 4;
            const int fc = l & 15;
            const size_t ibase =
                (((((size_t)(b * 8 + h) * 8 + jc) * 4 + ks4) * 4 + kg) * 6 + ft) * 128 +
                fc * 8 + e0;
            ushort4 pk;
            pk.x = f2bf(acc[fr][cg][0]);
            pk.y = f2bf(acc[fr][cg][1]);
            pk.z = f2bf(acc[fr][cg][2]);
            pk.w = f2bf(acc[fr][cg][3]);
            *(ushort4*)&Vb[ibase] = pk;
        }
    }

    // Epilogue 2: f1/f2 partial sums. Per (fr,cg): rows jglob..+3, cols
    // g0..g0+15 (single head h since 16 | 96). Reduce over the 16 col-lanes.
#pragma unroll
    for (int cg = 0; cg < 2; ++cg) {
        const int c = bx * 64 + wc * 32 + cg * 16 + (l & 15);
        const int h = c / 96;
        const int f = c - h * 96;
        const float av1 = a[f];
        const float av2 = a[96 + f];
#pragma unroll
        for (int fr = 0; fr < 2; ++fr) {
            const int jglob = row0 + wr * 32 + fr * 16 + (l >> 4) * 4;
            const int b = jglob >> 10;
            const int n0 = jglob & 1023;
#pragma unroll
            for (int r = 0; r < 4; ++r) {
                float s1 = acc[fr][cg][r] * av1;
                float s2 = acc[fr][cg][r] * av2;
#pragma unroll
                for (int m = 1; m < 16; m <<= 1) {
                    s1 += __shfl_xor(s1, m);
                    s2 += __shfl_xor(s2, m);
                }
                if ((l & 15) == 0) {
                    const int idx = (((b << 3) + h) << 10) | (n0 + r);
                    atomicAdd(&f1[idx], s1);
                    atomicAdd(&f2[idx], s2);
                }
            }
        }
    }
}

// ---------------------------------------------------------------------------
// attn7_k: V-reuse attention (round-8 verified). Block = 4 waves x 64 rows,
// V staged per 128-j chunk in dbuf LDS via global_load_lds.
// ---------------------------------------------------------------------------
__global__ __launch_bounds__(256) void attn7_k(const unsigned short* __restrict__ Vb,
                                               const float* __restrict__ f1,
                                               const float* __restrict__ f2,
                                               const int* __restrict__ mask,
                                               float* __restrict__ out) {
    __shared__ __align__(16) unsigned short Vs[2][12288];
    __shared__ float g2_s[1024];

    const int tid = threadIdx.x;
    const int lane = tid & 63;
    const int w = tid >> 6;
    const int kg = lane >> 4;
    const int fcr = lane & 15;
    const int nid = (blockIdx.x & 7) * 64 + (blockIdx.x >> 3);
    const int it = nid & 15;       // 16 i-tiles of 64 rows
    const int bh = nid >> 4;
    const int b = bh >> 3;
    const int h = bh & 7;

    const size_t vbase = (size_t)bh * 98304;

    for (int j = tid; j < 1024; j += 256) {
        float fv = f2[bh * 1024 + j] * LOG2E;
        g2_s[j] = (mask[b * 1024 + j] != 0) ? fv : -20000.f;
    }

    const float f1v = f1[bh * 1024 + it * 64 + w * 16 + fcr] * LOG2E;

#pragma unroll
    for (int r = 0; r < 6; ++r) {
        const int s = r * 256 + tid;           // 16B slot 0..1535
        gload16(Vb + vbase + (size_t)s * 8, &Vs[0][s * 8]);
    }

    f32x4 acc[6];
#pragma unroll
    for (int ft = 0; ft < 6; ++ft) acc[ft] = (f32x4){0.f, 0.f, 0.f, 0.f};
    float ls = 0.f;

    int buf = 0;
    for (int c = 0; c < 8; ++c) {
        __syncthreads();
        if (c < 7) {
#pragma unroll
            for (int r = 0; r < 6; ++r) {
                const int s = r * 256 + tid;
                gload16(Vb + vbase + (size_t)(c + 1) * 12288 + (size_t)s * 8,
                        &Vs[buf ^ 1][s * 8]);
            }
        }
        const unsigned short* vsb = &Vs[buf][0];
#pragma unroll
        for (int ks = 0; ks < 4; ++ks) {
            s8 af;
            const int jb = c * 128 + ks * 32 + kg * 8;
            float4 ga = *(const float4*)&g2_s[jb];
            float4 gb = *(const float4*)&g2_s[jb + 4];
            float g[8] = {ga.x, ga.y, ga.z, ga.w, gb.x, gb.y, gb.z, gb.w};
#pragma unroll
            for (int e = 0; e < 8; ++e) {
                float t = f1v + g[e];
                float lr = fmaxf(t, 0.f) + ALPHA * fminf(t, 0.f);
                float pe = exp2f(lr);
                ls += pe;
                af[e] = (short)f2bf(pe);
            }
            const unsigned short* vp = vsb + ((ks * 4 + kg) * 6) * 128 + fcr * 8;
#pragma unroll
            for (int ft = 0; ft < 6; ++ft) {
                us8 bvu = *(const us8*)(vp + ft * 128);
                acc[ft] = __builtin_amdgcn_mfma_f32_16x16x32_bf16(
                    af, (s8)bvu, acc[ft], 0, 0, 0);
            }
        }
        buf ^= 1;
    }

    ls += __shfl_xor(ls, 16);
    ls += __shfl_xor(ls, 32);
    float inv[4];
#pragma unroll
    for (int r = 0; r < 4; ++r) inv[r] = 1.0f / __shfl(ls, kg * 4 + r);

    const int irow0 = it * 64 + w * 16 + kg * 4;
#pragma unroll
    for (int r = 0; r < 4; ++r) {
        const size_t ob = (size_t)(b * 1024 + irow0 + r) * 768 + h * 96 + fcr;
#pragma unroll
        for (int ft = 0; ft < 6; ++ft) {
            out[ob + ft * 16] = acc[ft][r] * inv[r];
        }
    }
}

extern "C" void kernel_launch(void* const* d_in, const int* in_sizes, int n_in,
                              void* d_out, int out_size, void* d_ws, size_t ws_size,
                              hipStream_t stream) {
    const float* X = (const float*)d_in[0];
    const int* mask = (const int*)d_in[1];
    const float* W = (const float*)d_in[2];
    const float* a = (const float*)d_in[3];
    float* out = (float*)d_out;
    char* ws = (char*)d_ws;

    unsigned short* Vb = (unsigned short*)(ws + VB_OFFB);
    unsigned short* Wb = (unsigned short*)(ws + WB_OFFB);
    float* f1 = (float*)(ws + F1_OFFB);
    float* f2 = (float*)(ws + F2_OFFB);

    prep_w<<<544, 256, 0, stream>>>(W, Wb, f1);   // f1,f2 contiguous: zeroed together
    gemm_f<<<768, 256, 0, stream>>>(X, Wb, a, Vb, f1, f2);
    attn7_k<<<512, 256, 0, stream>>>(Vb, f1, f2, mask, out);
}

// Round 11
// 50.836 us; speedup vs baseline: 4.4373x; 1.4330x over previous
//
#include <hip/hip_runtime.h>
#include <hip/hip_bf16.h>

#define ALPHA 0.2f
#define LOG2E 1.44269504f

// ws layout (bytes)
#define VB_OFFB 0                        // Vb: bf16 swizzled V, 6291456 B
#define XB_OFFB 6291456                  // Xb: bf16 X, 6291456 B
#define WB_OFFB (XB_OFFB + 6291456)      // Wb: bf16 swizzled W, 1179648 B
#define F1_OFFB (WB_OFFB + 1179648)      // f1: 32768 f32
#define F2_OFFB (F1_OFFB + 131072)       // f2: 32768 f32

typedef __attribute__((ext_vector_type(8))) unsigned short us8;
typedef __attribute__((ext_vector_type(8))) short s8;
typedef __attribute__((ext_vector_type(4))) float f32x4;

__device__ inline unsigned short f2bf(float x) {
    __hip_bfloat16 h = __float2bfloat16(x);
    return reinterpret_cast<unsigned short&>(h);
}

__device__ __forceinline__ void gload16(const void* g, void* lds) {
    __builtin_amdgcn_global_load_lds((const unsigned int*)g, (unsigned int*)lds,
                                     16, 0, 0);
}

// ---------------------------------------------------------------------------
// prep_all: one launch for all preprocessing.
//   blocks 0..1535:    X fp32 -> Xb bf16 (row-major)
//   blocks 1536..1823: W fp32 -> Wb bf16 B-frag order
//                      Wb[kt(12)][ct(12)][cg4(4)][ks(2)][lane(64)][e(8)]
//   blocks 1824..2079: zero f1/f2 (65536 floats, contiguous)
// ---------------------------------------------------------------------------
__global__ __launch_bounds__(256) void prep_all(const float* __restrict__ X,
                                                const float* __restrict__ W,
                                                unsigned short* __restrict__ Xb,
                                                unsigned short* __restrict__ Wb,
                                                float* __restrict__ f12z) {
    if (blockIdx.x < 1536) {
        const int i = (blockIdx.x * 256 + threadIdx.x) * 8;
        float4 v0 = *(const float4*)&X[i];
        float4 v1 = *(const float4*)&X[i + 4];
        ushort4 p0, p1;
        p0.x = f2bf(v0.x); p0.y = f2bf(v0.y); p0.z = f2bf(v0.z); p0.w = f2bf(v0.w);
        p1.x = f2bf(v1.x); p1.y = f2bf(v1.y); p1.z = f2bf(v1.z); p1.w = f2bf(v1.w);
        *(ushort4*)&Xb[i] = p0;
        *(ushort4*)&Xb[i + 4] = p1;
    } else if (blockIdx.x < 1824) {
        const int id = (blockIdx.x - 1536) * 256 + threadIdx.x;   // 0..73727
        const int l = id & 63;
        const int ks = (id >> 6) & 1;
        const int cg4 = (id >> 7) & 3;
        const int kc = id >> 9;                          // kt*12 + ct
        const int kt = kc / 12;
        const int ct = kc - kt * 12;
        const int k0 = kt * 64 + ks * 32 + (l >> 4) * 8;
        const int n = ct * 64 + cg4 * 16 + (l & 15);
        ushort4 p0, p1;
        p0.x = f2bf(W[(size_t)(k0 + 0) * 768 + n]);
        p0.y = f2bf(W[(size_t)(k0 + 1) * 768 + n]);
        p0.z = f2bf(W[(size_t)(k0 + 2) * 768 + n]);
        p0.w = f2bf(W[(size_t)(k0 + 3) * 768 + n]);
        p1.x = f2bf(W[(size_t)(k0 + 4) * 768 + n]);
        p1.y = f2bf(W[(size_t)(k0 + 5) * 768 + n]);
        p1.z = f2bf(W[(size_t)(k0 + 6) * 768 + n]);
        p1.w = f2bf(W[(size_t)(k0 + 7) * 768 + n]);
        *(ushort4*)&Wb[(size_t)id * 8 + 0] = p0;
        *(ushort4*)&Wb[(size_t)id * 8 + 4] = p1;
    } else {
        const int idx = (blockIdx.x - 1824) * 256 + threadIdx.x;  // 0..65535
        f12z[idx] = 0.f;
    }
}

// ---------------------------------------------------------------------------
// gemm_mfma_f: round-4 verified LDS gemm core (coalesced global_load_lds,
// A-side XOR swizzle, lane-linear Wb) + fused epilogues: Vb swizzled store
// and f1/f2 = Wh.a1/a2 (16-lane shfl reduce + fp32 atomicAdd; 12 adds per
// address). Grid 768, XCD-chunked bijective swizzle.
// ---------------------------------------------------------------------------
__global__ __launch_bounds__(256) void gemm_mfma_f(const unsigned short* __restrict__ Xb,
                                                   const unsigned short* __restrict__ Wb,
                                                   const float* __restrict__ a,
                                                   unsigned short* __restrict__ Vb,
                                                   float* __restrict__ f1,
                                                   float* __restrict__ f2) {
    __shared__ __align__(16) unsigned short Xs[2][4096];
    __shared__ __align__(16) unsigned short Ws[2][4096];

    const int tid = threadIdx.x;
    const int l = tid & 63;
    const int w = tid >> 6;
    const int wr = w >> 1, wc = w & 1;
    const int nid = (blockIdx.x & 7) * 96 + (blockIdx.x >> 3);
    const int bx = nid % 12;             // N-tile (64 cols)
    const int row0 = (nid / 12) * 64;    // M-tile (64 rows)

    const int xrow_base = w * 16 + (l >> 3);
    const int xkb_log8 = ((l & 7) ^ (l >> 3)) * 8;

    f32x4 acc[2][2];
#pragma unroll
    for (int i = 0; i < 2; ++i)
#pragma unroll
        for (int j = 0; j < 2; ++j) acc[i][j] = (f32x4){0.f, 0.f, 0.f, 0.f};

    {
#pragma unroll
        for (int q = 0; q < 2; ++q) {
            const int g16 = w * 2 + q;
            gload16(Xb + (size_t)(row0 + xrow_base + q * 8) * 768 + xkb_log8,
                    &Xs[0][g16 * 512]);
            gload16(Wb + (size_t)(0 * 12 + bx) * 4096 + g16 * 512 + l * 8,
                    &Ws[0][g16 * 512]);
        }
    }

    int buf = 0;
    for (int kt = 0; kt < 12; ++kt) {
        __syncthreads();
        if (kt < 11) {
            const int k0n = (kt + 1) * 64;
#pragma unroll
            for (int q = 0; q < 2; ++q) {
                const int g16 = w * 2 + q;
                gload16(Xb + (size_t)(row0 + xrow_base + q * 8) * 768 + k0n + xkb_log8,
                        &Xs[buf ^ 1][g16 * 512]);
                gload16(Wb + (size_t)((kt + 1) * 12 + bx) * 4096 + g16 * 512 + l * 8,
                        &Ws[buf ^ 1][g16 * 512]);
            }
        }
#pragma unroll
        for (int ks = 0; ks < 2; ++ks) {
            s8 af[2], bfr[2];
#pragma unroll
            for (int fr = 0; fr < 2; ++fr) {
                const int row = wr * 32 + fr * 16 + (l & 15);
                const int slot = (ks * 4 + (l >> 4)) ^ (row & 7);
                af[fr] = *(const s8*)((const char*)&Xs[buf][0] + row * 128 + slot * 16);
            }
#pragma unroll
            for (int cg = 0; cg < 2; ++cg) {
                bfr[cg] = *(const s8*)((const char*)&Ws[buf][0] +
                                       (((wc * 2 + cg) * 2 + ks) * 64 + l) * 16);
            }
#pragma unroll
            for (int fr = 0; fr < 2; ++fr)
#pragma unroll
                for (int cg = 0; cg < 2; ++cg)
                    acc[fr][cg] = __builtin_amdgcn_mfma_f32_16x16x32_bf16(
                        af[fr], bfr[cg], acc[fr][cg], 0, 0, 0);
        }
        buf ^= 1;
    }

    // Epilogue 1: Vb swizzled bf16 store. C/D: col=l&15, row=(l>>4)*4+reg.
#pragma unroll
    for (int fr = 0; fr < 2; ++fr) {
#pragma unroll
        for (int cg = 0; cg < 2; ++cg) {
            const int jglob = row0 + wr * 32 + fr * 16 + (l >> 4) * 4;
            const int b = jglob >> 10;
            const int jn = jglob & 1023;
            const int jc = jn >> 7;
            const int ks4 = (jn >> 5) & 3;
            const int kg = (jn >> 3) & 3;
            const int e0 = jn & 7;
            const int g0 = bx * 64 + wc * 32 + cg * 16;
            const int h = g0 / 96;
            const int ft = (g0 - h * 96) >> 4;
            const int fc = l & 15;
            const size_t ibase =
                (((((size_t)(b * 8 + h) * 8 + jc) * 4 + ks4) * 4 + kg) * 6 + ft) * 128 +
                fc * 8 + e0;
            ushort4 pk;
            pk.x = f2bf(acc[fr][cg][0]);
            pk.y = f2bf(acc[fr][cg][1]);
            pk.z = f2bf(acc[fr][cg][2]);
            pk.w = f2bf(acc[fr][cg][3]);
            *(ushort4*)&Vb[ibase] = pk;
        }
    }

    // Epilogue 2: f1/f2 partial sums (verified in round 10).
#pragma unroll
    for (int cg = 0; cg < 2; ++cg) {
        const int c = bx * 64 + wc * 32 + cg * 16 + (l & 15);
        const int h = c / 96;
        const int f = c - h * 96;
        const float av1 = a[f];
        const float av2 = a[96 + f];
#pragma unroll
        for (int fr = 0; fr < 2; ++fr) {
            const int jglob = row0 + wr * 32 + fr * 16 + (l >> 4) * 4;
            const int b = jglob >> 10;
            const int n0 = jglob & 1023;
#pragma unroll
            for (int r = 0; r < 4; ++r) {
                float s1 = acc[fr][cg][r] * av1;
                float s2 = acc[fr][cg][r] * av2;
#pragma unroll
                for (int m = 1; m < 16; m <<= 1) {
                    s1 += __shfl_xor(s1, m);
                    s2 += __shfl_xor(s2, m);
                }
                if ((l & 15) == 0) {
                    const int idx = (((b << 3) + h) << 10) | (n0 + r);
                    atomicAdd(&f1[idx], s1);
                    atomicAdd(&f2[idx], s2);
                }
            }
        }
    }
}

// ---------------------------------------------------------------------------
// attn7_k: V-reuse attention (round-8 verified). Block = 4 waves x 64 rows,
// V staged per 128-j chunk in dbuf LDS via global_load_lds.
// ---------------------------------------------------------------------------
__global__ __launch_bounds__(256) void attn7_k(const unsigned short* __restrict__ Vb,
                                               const float* __restrict__ f1,
                                               const float* __restrict__ f2,
                                               const int* __restrict__ mask,
                                               float* __restrict__ out) {
    __shared__ __align__(16) unsigned short Vs[2][12288];
    __shared__ float g2_s[1024];

    const int tid = threadIdx.x;
    const int lane = tid & 63;
    const int w = tid >> 6;
    const int kg = lane >> 4;
    const int fcr = lane & 15;
    const int nid = (blockIdx.x & 7) * 64 + (blockIdx.x >> 3);
    const int it = nid & 15;       // 16 i-tiles of 64 rows
    const int bh = nid >> 4;
    const int b = bh >> 3;
    const int h = bh & 7;

    const size_t vbase = (size_t)bh * 98304;

    for (int j = tid; j < 1024; j += 256) {
        float fv = f2[bh * 1024 + j] * LOG2E;
        g2_s[j] = (mask[b * 1024 + j] != 0) ? fv : -20000.f;
    }

    const float f1v = f1[bh * 1024 + it * 64 + w * 16 + fcr] * LOG2E;

#pragma unroll
    for (int r = 0; r < 6; ++r) {
        const int s = r * 256 + tid;           // 16B slot 0..1535
        gload16(Vb + vbase + (size_t)s * 8, &Vs[0][s * 8]);
    }

    f32x4 acc[6];
#pragma unroll
    for (int ft = 0; ft < 6; ++ft) acc[ft] = (f32x4){0.f, 0.f, 0.f, 0.f};
    float ls = 0.f;

    int buf = 0;
    for (int c = 0; c < 8; ++c) {
        __syncthreads();
        if (c < 7) {
#pragma unroll
            for (int r = 0; r < 6; ++r) {
                const int s = r * 256 + tid;
                gload16(Vb + vbase + (size_t)(c + 1) * 12288 + (size_t)s * 8,
                        &Vs[buf ^ 1][s * 8]);
            }
        }
        const unsigned short* vsb = &Vs[buf][0];
#pragma unroll
        for (int ks = 0; ks < 4; ++ks) {
            s8 af;
            const int jb = c * 128 + ks * 32 + kg * 8;
            float4 ga = *(const float4*)&g2_s[jb];
            float4 gb = *(const float4*)&g2_s[jb + 4];
            float g[8] = {ga.x, ga.y, ga.z, ga.w, gb.x, gb.y, gb.z, gb.w};
#pragma unroll
            for (int e = 0; e < 8; ++e) {
                float t = f1v + g[e];
                float lr = fmaxf(t, 0.f) + ALPHA * fminf(t, 0.f);
                float pe = exp2f(lr);
                ls += pe;
                af[e] = (short)f2bf(pe);
            }
            const unsigned short* vp = vsb + ((ks * 4 + kg) * 6) * 128 + fcr * 8;
#pragma unroll
            for (int ft = 0; ft < 6; ++ft) {
                us8 bvu = *(const us8*)(vp + ft * 128);
                acc[ft] = __builtin_amdgcn_mfma_f32_16x16x32_bf16(
                    af, (s8)bvu, acc[ft], 0, 0, 0);
            }
        }
        buf ^= 1;
    }

    ls += __shfl_xor(ls, 16);
    ls += __shfl_xor(ls, 32);
    float inv[4];
#pragma unroll
    for (int r = 0; r < 4; ++r) inv[r] = 1.0f / __shfl(ls, kg * 4 + r);

    const int irow0 = it * 64 + w * 16 + kg * 4;
#pragma unroll
    for (int r = 0; r < 4; ++r) {
        const size_t ob = (size_t)(b * 1024 + irow0 + r) * 768 + h * 96 + fcr;
#pragma unroll
        for (int ft = 0; ft < 6; ++ft) {
            out[ob + ft * 16] = acc[ft][r] * inv[r];
        }
    }
}

extern "C" void kernel_launch(void* const* d_in, const int* in_sizes, int n_in,
                              void* d_out, int out_size, void* d_ws, size_t ws_size,
                              hipStream_t stream) {
    const float* X = (const float*)d_in[0];
    const int* mask = (const int*)d_in[1];
    const float* W = (const float*)d_in[2];
    const float* a = (const float*)d_in[3];
    float* out = (float*)d_out;
    char* ws = (char*)d_ws;

    unsigned short* Vb = (unsigned short*)(ws + VB_OFFB);
    unsigned short* Xb = (unsigned short*)(ws + XB_OFFB);
    unsigned short* Wb = (unsigned short*)(ws + WB_OFFB);
    float* f1 = (float*)(ws + F1_OFFB);
    float* f2 = (float*)(ws + F2_OFFB);

    prep_all<<<2080, 256, 0, stream>>>(X, W, Xb, Wb, f1);  // f1,f2 contiguous
    gemm_mfma_f<<<768, 256, 0, stream>>>(Xb, Wb, a, Vb, f1, f2);
    attn7_k<<<512, 256, 0, stream>>>(Vb, f1, f2, mask, out);
}